// Round 3
// baseline (352.549 us; speedup 1.0000x reference)
//
#include <hip/hip_runtime.h>
#include <hip/hip_bf16.h>
#include <math.h>

// ---------------------------------------------------------------------------
// TemporalSSMPatchwise: b=8,t=15,H=480,W=640, PS=8 -> hp=60,wp=80, n=4800
// d=64, P=32, pp=64.  N_seq = 38400.
// Weights = MFMA A-operands (row-permuted so D-layout == next B-layout).
// t-PARALLEL scan: block = 4 waves on the SAME 16 seqs, wave w handles
// t-chunk [4w, 4w+4) (w=3: 12..14).  Each wave runs the standard recurrence
// on its chunk -> S_w, scales by Lbar^(14 - t_hi(w)), combines via LDS;
// wave 3 runs the head (incl. LN3 + bf16 pack) and writes zbuf.
// K2 = pure W_out GEMM from zbuf + pixel-shuffle stores.
// MFMA 16x16x32 bf16: A[m=lane&15][k=qd*8+j], B[k][n=lane&15],
// D: col=lane&15, row=qd*4+reg.
// ---------------------------------------------------------------------------

typedef __attribute__((ext_vector_type(8))) short short8;
typedef __attribute__((ext_vector_type(4))) float f32x4;

#define MFMA16(a, b, c) __builtin_amdgcn_mfma_f32_16x16x32_bf16((a), (b), (c), 0, 0, 0)

__device__ __forceinline__ short f2bf(float f) {
  union { float f; unsigned u; } v; v.f = f;
  unsigned r = (v.u + 0x7fffu + ((v.u >> 16) & 1u)) >> 16;  // RNE
  return (short)r;
}
__device__ __forceinline__ void pkpair(short8& o, int i, float a, float b) {
  union { __hip_bfloat162 h; short s[2]; } u;
  u.h = __float22bfloat162_rn(float2{a, b});
  o[i] = u.s[0]; o[i + 1] = u.s[1];
}
__device__ __forceinline__ short8 packfrag(const f32x4& a, const f32x4& b) {
  short8 o;
  pkpair(o, 0, a[0], a[1]); pkpair(o, 2, a[2], a[3]);
  pkpair(o, 4, b[0], b[1]); pkpair(o, 6, b[2], b[3]);
  return o;
}
__device__ __forceinline__ float geluf(float x) {
  return 0.5f * x * (1.0f + erff(x * 0.70710678118654752f));
}
// weight-row permutation: A-row a = i*16+m  ->  actual channel
__device__ __forceinline__ int ecmap(int i, int m) {
  return (i >> 1) * 32 + (m >> 2) * 8 + (i & 1) * 4 + (m & 3);
}
__device__ __forceinline__ void bbar_factors(const float* Lre, const float* Lim,
                                             const float* lstep, int p,
                                             float& fre, float& fim) {
  float st = expf(lstep[p]);
  float lr = Lre[p], li = Lim[p];
  float er = expf(lr * st);
  float lbr = er * cosf(li * st), lbi = er * sinf(li * st);
  float u = lbr - 1.0f, v = lbi;
  float den = lr * lr + li * li;
  fre = (u * lr + v * li) / den;
  fim = (v * lr - u * li) / den;
}

// ---------------------------------------------------------------------------
// K0: pack 176 A-operand fragments (1 KB each) + bu0.  (unchanged format)
// ids: 0..7 W_embed | 8..15 Bbar'(g1-folded) | 16..23 Cc2(mask-folded)
//      24..39 W_enc | 40..47 W_dec | 48..175 W_out
// ---------------------------------------------------------------------------
__global__ __launch_bounds__(256) void k0_prep(
    const float* __restrict__ W_embed, const float* __restrict__ g1,
    const float* __restrict__ be1, const float* __restrict__ Lre,
    const float* __restrict__ Lim, const float* __restrict__ Bre,
    const float* __restrict__ Bim, const float* __restrict__ Cre,
    const float* __restrict__ Cim, const float* __restrict__ lstep,
    const float* __restrict__ W_enc, const float* __restrict__ W_dec,
    const float* __restrict__ W_out, short* __restrict__ wimg,
    float* __restrict__ bu0) {
  const int bid = blockIdx.x;
  if (bid == 44) {  // bu0[q] = sum_d beta1[d] * Bbar_comp[p][d]
    int q = threadIdx.x;
    if (q < 64) {
      int c = q >> 5, p = q & 31;
      float fre, fim; bbar_factors(Lre, Lim, lstep, p, fre, fim);
      float s = 0.f;
      for (int d = 0; d < 64; ++d) {
        float br = Bre[p * 64 + d], bi = Bim[p * 64 + d];
        float val = c ? (fre * bi + fim * br) : (fre * br - fim * bi);
        s += be1[d] * val;
      }
      bu0[q] = s;
    }
    return;
  }
  const int w = threadIdx.x >> 6, lane = threadIdx.x & 63;
  const int m = lane & 15, qd = lane >> 4;
  const int f = bid * 4 + w;
  short v[8];
  if (f < 8) {
    int i = f >> 1, kt = f & 1, chan = ecmap(i, m), k0 = kt * 32 + qd * 8;
#pragma unroll
    for (int j = 0; j < 8; ++j) v[j] = f2bf(W_embed[chan * 64 + k0 + j]);
  } else if (f < 16) {
    int fi = f - 8, i = fi >> 1, kt = fi & 1;
    int comp = i & 1, p = (i >> 1) * 16 + m, d0 = kt * 32 + qd * 8;
    float fre, fim; bbar_factors(Lre, Lim, lstep, p, fre, fim);
#pragma unroll
    for (int j = 0; j < 8; ++j) {
      int d = d0 + j;
      float br = Bre[p * 64 + d], bi = Bim[p * 64 + d];
      float val = comp ? (fre * bi + fim * br) : (fre * br - fim * bi);
      v[j] = f2bf(g1[d] * val);
    }
  } else if (f < 24) {
    int fi = f - 16, i = fi >> 1, kt = fi & 1, chan = ecmap(i, m);
#pragma unroll
    for (int j = 0; j < 8; ++j) {
      int comp = j >> 2, p = kt * 16 + qd * 4 + (j & 3);
      float stp = expf(lstep[p]);
      float fr = stp * fabsf(Lim[p]) * (1.0f / 6.28318530717958648f);
      float msk = (fr < 0.5f) ? 1.f : 0.f;
      float val = comp ? -Cim[chan * 32 + p] * msk : Cre[chan * 32 + p] * msk;
      v[j] = f2bf(val);
    }
  } else if (f < 40) {
    int fi = f - 24, i = fi >> 1, kt = fi & 1;
    int row = (i < 4) ? ecmap(i, m) : 64 + ecmap(i - 4, m);
#pragma unroll
    for (int j = 0; j < 8; ++j) v[j] = f2bf(W_enc[row * 64 + kt * 32 + qd * 8 + j]);
  } else if (f < 48) {
    int fi = f - 40, i = fi >> 1, kt = fi & 1, row = ecmap(i, m);
#pragma unroll
    for (int j = 0; j < 8; ++j) v[j] = f2bf(W_dec[row * 64 + kt * 32 + qd * 8 + j]);
  } else {
    int fi = f - 48, i = fi >> 1, kt = fi & 1, row = i * 16 + m;  // natural
#pragma unroll
    for (int j = 0; j < 8; ++j) v[j] = f2bf(W_out[row * 64 + kt * 32 + qd * 8 + j]);
  }
  short8 sv;
#pragma unroll
  for (int j = 0; j < 8; ++j) sv[j] = v[j];
  *(short8*)&wimg[(f * 64 + lane) * 8] = sv;
}

// ---------------------------------------------------------------------------
// K1: t-parallel scan + head.  grid 2400, block 256 = 4 waves x same 16 seqs.
// ---------------------------------------------------------------------------
__global__ __launch_bounds__(256) void k1_fused(
    const float* __restrict__ x, const short* __restrict__ wimg_g,
    const float* __restrict__ bu0_g, const float* __restrict__ Lre,
    const float* __restrict__ Lim, const float* __restrict__ lstep,
    const float* __restrict__ bemb, const float* __restrict__ g1,
    const float* __restrict__ be1, const float* __restrict__ Dv,
    const float* __restrict__ g2, const float* __restrict__ be2,
    const float* __restrict__ g3, const float* __restrict__ be3,
    short* __restrict__ zbuf) {
  __shared__ short wlds[16 * 512];   // embed(0..7)+Bbar(8..15) frags, 16 KB
  __shared__ float part[3 * 16 * 64];  // 12 KB partial states from waves 0..2
  {
    float4* dst = (float4*)wlds;
    const float4* src = (const float4*)wimg_g;
    for (int i = threadIdx.x; i < 1024; i += 256) dst[i] = src[i];
  }
  __syncthreads();
#define WF(id) (*(const short8*)&wlds[(id) * 512 + lane * 8])
#define GF(id) (*(const short8*)&wimg_g[(id) * 512 + lane * 8])

  const int wv = threadIdx.x >> 6, lane = threadIdx.x & 63;
  const int s = lane & 15, qd = lane >> 4;
  const int sbase = blockIdx.x * 16;
  const int b_i = sbase / 4800;
  const int pr = sbase % 4800;
  const int ph = pr / 80;
  const int pw0 = pr % 80;
  const int t0 = wv * 4, tn = (wv == 3) ? 3 : 4;
  const float* xbase =
      x + ((b_i * 15 + t0) * 480 + ph * 8) * 640 + (pw0 + s) * 8;

  int cb[4];
  f32x4 bec[4], bu0c[4];
#pragma unroll
  for (int nt = 0; nt < 4; ++nt) {
    cb[nt] = (nt >> 1) * 32 + qd * 8 + (nt & 1) * 4;
    bec[nt] = *(const f32x4*)(bemb + cb[nt]);
    bu0c[nt] = *(const f32x4*)(bu0_g + (nt & 1) * 32 + (nt >> 1) * 16 + qd * 4);
  }
  f32x4 lbr[2], lbi[2];
#pragma unroll
  for (int k = 0; k < 2; ++k)
#pragma unroll
    for (int r = 0; r < 4; ++r) {
      int p = k * 16 + qd * 4 + r;
      float st = expf(lstep[p]);
      float er = expf(Lre[p] * st);
      lbr[k][r] = er * cosf(Lim[p] * st);
      lbi[k][r] = er * sinf(Lim[p] * st);
    }

  const f32x4 zf = {0.f, 0.f, 0.f, 0.f};
  f32x4 state[4] = {zf, zf, zf, zf};
  f32x4 xh[4];

  f32x4 vcur[4], vnext[4];
#pragma unroll
  for (int kt = 0; kt < 2; ++kt) {
    const float* rp = xbase + (kt * 4 + qd) * 640;
    vcur[kt * 2] = *(const f32x4*)rp;
    vcur[kt * 2 + 1] = *(const f32x4*)(rp + 4);
  }

  for (int it = 0; it < tn; ++it) {
    if (it + 1 < tn) {
      const float* xn = xbase + (it + 1) * 307200;
#pragma unroll
      for (int kt = 0; kt < 2; ++kt) {
        const float* rp = xn + (kt * 4 + qd) * 640;
        vnext[kt * 2] = *(const f32x4*)rp;
        vnext[kt * 2 + 1] = *(const f32x4*)(rp + 4);
      }
    }
    short8 pa0 = packfrag(vcur[0], vcur[1]);
    short8 pa1 = packfrag(vcur[2], vcur[3]);
    f32x4 c1[4];
#pragma unroll
    for (int i = 0; i < 4; ++i) {
      f32x4 acc = MFMA16(WF(i * 2), pa0, zf);
      acc = MFMA16(WF(i * 2 + 1), pa1, acc);
      c1[i] = acc + bec[i];
    }
    float sm = 0.f, sq = 0.f;
#pragma unroll
    for (int nt = 0; nt < 4; ++nt)
#pragma unroll
      for (int i = 0; i < 4; ++i) { sm += c1[nt][i]; sq += c1[nt][i] * c1[nt][i]; }
    sm += __shfl_xor(sm, 16); sq += __shfl_xor(sq, 16);
    sm += __shfl_xor(sm, 32); sq += __shfl_xor(sq, 32);
    float mean = sm * 0.015625f;
    float rstd = rsqrtf(sq * 0.015625f - mean * mean + 1e-5f);
#pragma unroll
    for (int nt = 0; nt < 4; ++nt) xh[nt] = (c1[nt] - mean) * rstd;
    short8 xa0 = packfrag(xh[0], xh[1]);
    short8 xa1 = packfrag(xh[2], xh[3]);
#pragma unroll
    for (int k = 0; k < 2; ++k) {
      f32x4 re = state[2 * k], im = state[2 * k + 1];
      state[2 * k]     = lbr[k] * re - lbi[k] * im + bu0c[2 * k];
      state[2 * k + 1] = lbr[k] * im + lbi[k] * re + bu0c[2 * k + 1];
    }
#pragma unroll
    for (int i = 0; i < 4; ++i) {
      state[i] = MFMA16(WF(8 + i * 2), xa0, state[i]);
      state[i] = MFMA16(WF(8 + i * 2 + 1), xa1, state[i]);
    }
#pragma unroll
    for (int q = 0; q < 4; ++q) vcur[q] = vnext[q];
  }

  short8 cc2f[8];
  if (wv < 3) {
    // scale S_w by Lbar^(14 - t_hi(w)):  e = 11, 7, 3 for w = 0,1,2
    int e = 11 - wv * 4;
    f32x4 pwr[2], pwi[2];
#pragma unroll
    for (int k = 0; k < 2; ++k) { pwr[k] = lbr[k]; pwi[k] = lbi[k]; }
    for (int it = 1; it < e; ++it)
#pragma unroll
      for (int k = 0; k < 2; ++k) {
        f32x4 nr = pwr[k] * lbr[k] - pwi[k] * lbi[k];
        f32x4 ni = pwr[k] * lbi[k] + pwi[k] * lbr[k];
        pwr[k] = nr; pwi[k] = ni;
      }
#pragma unroll
    for (int k = 0; k < 2; ++k) {
      f32x4 re = state[2 * k], im = state[2 * k + 1];
      state[2 * k]     = pwr[k] * re - pwi[k] * im;
      state[2 * k + 1] = pwr[k] * im + pwi[k] * re;
    }
#pragma unroll
    for (int i = 0; i < 4; ++i)
#pragma unroll
      for (int r = 0; r < 4; ++r)
        part[((wv * 16 + i * 4 + r) << 6) + lane] = state[i][r];
  } else {
    // prefetch Cc2 frags while other waves finish
#pragma unroll
    for (int i = 0; i < 8; ++i) cc2f[i] = GF(16 + i);
  }
  __syncthreads();
  if (wv != 3) return;

  // ---- wave 3: combine partials + head ----
#pragma unroll
  for (int w = 0; w < 3; ++w)
#pragma unroll
    for (int i = 0; i < 4; ++i)
#pragma unroll
      for (int r = 0; r < 4; ++r)
        state[i][r] += part[((w * 16 + i * 4 + r) << 6) + lane];

  f32x4 g1c[4], b1c[4], Dc[4], g2c[4], b2c[4];
#pragma unroll
  for (int nt = 0; nt < 4; ++nt) {
    g1c[nt] = *(const f32x4*)(g1 + cb[nt]);
    b1c[nt] = *(const f32x4*)(be1 + cb[nt]);
    Dc[nt] = *(const f32x4*)(Dv + cb[nt]);
    g2c[nt] = *(const f32x4*)(g2 + cb[nt]);
    b2c[nt] = *(const f32x4*)(be2 + cb[nt]);
  }
  f32x4 fxl[4];
#pragma unroll
  for (int nt = 0; nt < 4; ++nt) fxl[nt] = xh[nt] * g1c[nt] + b1c[nt];

  short8 xsa0 = packfrag(state[0], state[1]);
  short8 xsa1 = packfrag(state[2], state[3]);
  f32x4 xbv[4];
#pragma unroll
  for (int i = 0; i < 4; ++i) {
    f32x4 acc = fxl[i] * Dc[i];
    acc = MFMA16(cc2f[i * 2], xsa0, acc);
    acc = MFMA16(cc2f[i * 2 + 1], xsa1, acc);
#pragma unroll
    for (int r = 0; r < 4; ++r) xbv[i][r] = geluf(acc[r]) + fxl[i][r];
  }
  float sm2 = 0.f, sq2 = 0.f;
#pragma unroll
  for (int nt = 0; nt < 4; ++nt)
#pragma unroll
    for (int i = 0; i < 4; ++i) { sm2 += xbv[nt][i]; sq2 += xbv[nt][i] * xbv[nt][i]; }
  sm2 += __shfl_xor(sm2, 16); sq2 += __shfl_xor(sq2, 16);
  sm2 += __shfl_xor(sm2, 32); sq2 += __shfl_xor(sq2, 32);
  float mean2 = sm2 * 0.015625f;
  float rstd2 = rsqrtf(sq2 * 0.015625f - mean2 * mean2 + 1e-5f);
  f32x4 fx2[4];
#pragma unroll
  for (int nt = 0; nt < 4; ++nt)
    fx2[nt] = (xbv[nt] - mean2) * rstd2 * g2c[nt] + b2c[nt];

  short8 fa0 = packfrag(fx2[0], fx2[1]);
  short8 fa1 = packfrag(fx2[2], fx2[3]);
  f32x4 e[8];
#pragma unroll
  for (int half = 0; half < 2; ++half) {
    short8 ef[8];
#pragma unroll
    for (int i = 0; i < 8; ++i) ef[i] = GF(24 + half * 8 + i);
#pragma unroll
    for (int i = 0; i < 4; ++i) {
      f32x4 acc = MFMA16(ef[i * 2], fa0, zf);
      e[half * 4 + i] = MFMA16(ef[i * 2 + 1], fa1, acc);
    }
  }
  f32x4 hv[4];
#pragma unroll
  for (int nt = 0; nt < 4; ++nt)
#pragma unroll
    for (int i = 0; i < 4; ++i) hv[nt][i] = e[nt][i] * geluf(e[nt + 4][i]);

  short8 df[8];
#pragma unroll
  for (int i = 0; i < 8; ++i) df[i] = GF(40 + i);
  short8 ha0 = packfrag(hv[0], hv[1]);
  short8 ha1 = packfrag(hv[2], hv[3]);
  f32x4 xo[4];
#pragma unroll
  for (int i = 0; i < 4; ++i) {
    f32x4 acc = fx2[i];
    acc = MFMA16(df[i * 2], ha0, acc);
    xo[i] = MFMA16(df[i * 2 + 1], ha1, acc);
  }

  // ---- LN3 + pack to bf16 B-operand layout, store zbuf ----
  float sm3 = 0.f, sq3 = 0.f;
#pragma unroll
  for (int nt = 0; nt < 4; ++nt)
#pragma unroll
    for (int i = 0; i < 4; ++i) { sm3 += xo[nt][i]; sq3 += xo[nt][i] * xo[nt][i]; }
  sm3 += __shfl_xor(sm3, 16); sq3 += __shfl_xor(sq3, 16);
  sm3 += __shfl_xor(sm3, 32); sq3 += __shfl_xor(sq3, 32);
  float mean3 = sm3 * 0.015625f;
  float rstd3 = rsqrtf(sq3 * 0.015625f - mean3 * mean3 + 1e-5f);
  f32x4 z[4];
#pragma unroll
  for (int nt = 0; nt < 4; ++nt) {
    f32x4 g3c = *(const f32x4*)(g3 + cb[nt]);
    f32x4 b3c = *(const f32x4*)(be3 + cb[nt]);
    z[nt] = (xo[nt] - mean3) * rstd3 * g3c + b3c;
  }
  short8 z0 = packfrag(z[0], z[1]);
  short8 z1 = packfrag(z[2], z[3]);
  *(short8*)&zbuf[(sbase + s) * 64 + qd * 8] = z0;
  *(short8*)&zbuf[(sbase + s) * 64 + 32 + qd * 8] = z1;
#undef WF
#undef GF
}

// ---------------------------------------------------------------------------
// K2: W_out(A-op) x z + b_out -> float4 pixel-shuffle stores.
// 256 thr = 4 waves x 16 seqs; block covers 64 seqs x 256 out-rows.
// ---------------------------------------------------------------------------
__global__ __launch_bounds__(256) void k2_head(
    const short* __restrict__ zbuf, const short* __restrict__ wout_img,
    const float* __restrict__ b_out, float* __restrict__ y) {
  __shared__ short wo[32 * 512];
  const int nqb = blockIdx.x & 3;
  const int mblk = blockIdx.x >> 2;
  {
    float4* dst = (float4*)wo;
    const float4* src = (const float4*)(wout_img + nqb * 32 * 512);
    for (int i = threadIdx.x; i < 2048; i += 256) dst[i] = src[i];
  }
  const int wv = threadIdx.x >> 6, lane = threadIdx.x & 63;
  const int s = lane & 15, qd = lane >> 4;
  const int sbase = mblk * 64 + wv * 16;
  const int seq = sbase + s;
  const int nq0 = nqb * 256;
  short8 zb0 = *(const short8*)&zbuf[seq * 64 + qd * 8];
  short8 zb1 = *(const short8*)&zbuf[seq * 64 + 32 + qd * 8];
  __syncthreads();

  const int bi2 = seq / 4800, prr = seq % 4800;
  const int phh = prr / 80, pww = prr % 80;
  const int obase = (bi2 * 16 * 480 + phh * 8) * 640 + pww * 8;

#pragma unroll
  for (int nt = 0; nt < 16; ++nt) {
    int o0 = nq0 + nt * 16 + qd * 4;
    f32x4 acc = *(const f32x4*)(b_out + o0);
    acc = MFMA16(*(const short8*)&wo[(nt * 2 + 0) * 512 + lane * 8], zb0, acc);
    acc = MFMA16(*(const short8*)&wo[(nt * 2 + 1) * 512 + lane * 8], zb1, acc);
    int c = o0 >> 6, pi = (o0 >> 3) & 7, pj = o0 & 7;
    *(f32x4*)&y[obase + c * 307200 + pi * 640 + pj] = acc;
  }
}

// ---------------------------------------------------------------------------
extern "C" void kernel_launch(void* const* d_in, const int* in_sizes, int n_in,
                              void* d_out, int out_size, void* d_ws, size_t ws_size,
                              hipStream_t stream) {
  const float* x       = (const float*)d_in[0];
  const float* W_embed = (const float*)d_in[1];
  const float* b_embed = (const float*)d_in[2];
  const float* g1      = (const float*)d_in[3];
  const float* beta1   = (const float*)d_in[4];
  const float* Lre     = (const float*)d_in[5];
  const float* Lim     = (const float*)d_in[6];
  const float* Bre     = (const float*)d_in[7];
  const float* Bim     = (const float*)d_in[8];
  const float* Cre     = (const float*)d_in[9];
  const float* Cim     = (const float*)d_in[10];
  const float* Dv      = (const float*)d_in[11];
  const float* lstep   = (const float*)d_in[12];
  const float* g2      = (const float*)d_in[13];
  const float* beta2   = (const float*)d_in[14];
  const float* W_enc   = (const float*)d_in[15];
  const float* W_dec   = (const float*)d_in[16];
  const float* g3      = (const float*)d_in[17];
  const float* beta3   = (const float*)d_in[18];
  const float* W_out   = (const float*)d_in[19];
  const float* b_out   = (const float*)d_in[20];
  float* y = (float*)d_out;

  short* wimg = (short*)d_ws;                          // 176 KB frag images
  float* bu0 = (float*)((char*)d_ws + 176 * 1024);     // 256 B
  short* zbuf = (short*)((char*)d_ws + 180 * 1024);    // 38400*64 bf16 = 4.9 MB

  k0_prep<<<dim3(45), dim3(256), 0, stream>>>(W_embed, g1, beta1, Lre, Lim,
                                              Bre, Bim, Cre, Cim, lstep,
                                              W_enc, W_dec, W_out, wimg, bu0);
  k1_fused<<<dim3(2400), dim3(256), 0, stream>>>(x, wimg, bu0, Lre, Lim, lstep,
                                                 b_embed, g1, beta1, Dv, g2,
                                                 beta2, g3, beta3, zbuf);
  k2_head<<<dim3(2400), dim3(256), 0, stream>>>(zbuf, wimg + 48 * 512, b_out, y);
}